// Round 9
// baseline (104.401 us; speedup 1.0000x reference)
//
#include <hip/hip_runtime.h>

// MemoryAugmentation: value[b,c] = softmax_m(x[b,c] . mem[m]) . mem
// B*C = 8192 rows, H*W = 7744 (= 1936 float4), M = 10 slots.
//
// R9: two-kernel split. R3 (88.45us) serializes read-phase and write-phase
// within each block (softmax dependency), and the 64-VGPR tier forbids
// register pipelining across that boundary (R4/R6 spilled). Split instead:
//   K1: scores + softmax -> probs[8192][10] in d_ws (read-only stream, 254MB,
//       ~half L3-resident -> can exceed HBM pin rate)
//   K2: out = probs . mem (pure nt-write stream 248MB + L2-resident mem)
// Each kernel reuses R3's exact verified phase body (component-wise FMA,
// 64-reg tier, nt stores for out only; probs written/read via plain L2 path).

#define RROWS   4
#define NM      10
#define NVEC    1936          // 7744 / 4 float4 per row
#define THREADS 256

typedef float f32x4 __attribute__((ext_vector_type(4)));

// ---------------- K1: scores + softmax -> probs ----------------
__global__ __launch_bounds__(THREADS)
void memaug_scores(const float* __restrict__ x,
                   const float* __restrict__ mem,
                   float* __restrict__ probs)
{
    const int tid = threadIdx.x;
    const long r0 = (long)blockIdx.x * RROWS;

    const f32x4* __restrict__ m4 = (const f32x4*)mem;
    const f32x4* __restrict__ xr = (const f32x4*)x + r0 * NVEC;

    float acc[RROWS][NM];
#pragma unroll
    for (int j = 0; j < RROWS; ++j)
#pragma unroll
        for (int m = 0; m < NM; ++m) acc[j][m] = 0.f;

    for (int iv = tid; iv < NVEC; iv += THREADS) {
        f32x4 xv[RROWS];
#pragma unroll
        for (int j = 0; j < RROWS; ++j)
            xv[j] = xr[j * NVEC + iv];
        f32x4 mv[NM];
#pragma unroll
        for (int m = 0; m < NM; ++m)
            mv[m] = m4[m * NVEC + iv];
#pragma unroll
        for (int m = 0; m < NM; ++m) {
#pragma unroll
            for (int j = 0; j < RROWS; ++j) {
                acc[j][m] += xv[j].x * mv[m].x + xv[j].y * mv[m].y
                           + xv[j].z * mv[m].z + xv[j].w * mv[m].w;
            }
        }
    }

#pragma unroll
    for (int j = 0; j < RROWS; ++j)
#pragma unroll
        for (int m = 0; m < NM; ++m) {
            float v = acc[j][m];
#pragma unroll
            for (int off = 32; off > 0; off >>= 1)
                v += __shfl_xor(v, off, 64);
            acc[j][m] = v;
        }

    __shared__ float red[4][RROWS][NM];
    const int wave = tid >> 6;
    const int lane = tid & 63;
    if (lane == 0) {
#pragma unroll
        for (int j = 0; j < RROWS; ++j)
#pragma unroll
            for (int m = 0; m < NM; ++m) red[wave][j][m] = acc[j][m];
    }
    __syncthreads();

    if (tid < RROWS) {
        const int j = tid;
        float s[NM];
        float mx = -1e30f;
#pragma unroll
        for (int m = 0; m < NM; ++m) {
            s[m] = red[0][j][m] + red[1][j][m] + red[2][j][m] + red[3][j][m];
            mx = fmaxf(mx, s[m]);
        }
        float sum = 0.f;
#pragma unroll
        for (int m = 0; m < NM; ++m) { s[m] = expf(s[m] - mx); sum += s[m]; }
        const float inv = 1.f / sum;
        float* pr = probs + (r0 + j) * NM;
#pragma unroll
        for (int m = 0; m < NM; ++m) pr[m] = s[m] * inv;
    }
}

// ---------------- K2: out rows = probs . mem ----------------
__global__ __launch_bounds__(THREADS)
void memaug_apply(const float* __restrict__ probs,
                  const float* __restrict__ mem,
                  float* __restrict__ out)
{
    const int tid = threadIdx.x;
    const long r0 = (long)blockIdx.x * RROWS;

    const f32x4* __restrict__ m4 = (const f32x4*)mem;
    f32x4* __restrict__ orow     = (f32x4*)out + r0 * NVEC;

    __shared__ float sh_p[RROWS * NM];
    if (tid < RROWS * NM) sh_p[tid] = probs[r0 * NM + tid];
    __syncthreads();

    float p[RROWS][NM];
#pragma unroll
    for (int j = 0; j < RROWS; ++j)
#pragma unroll
        for (int m = 0; m < NM; ++m) p[j][m] = sh_p[j * NM + m];

    for (int iv = tid; iv < NVEC; iv += THREADS) {
        f32x4 mv[NM];
#pragma unroll
        for (int m = 0; m < NM; ++m)
            mv[m] = m4[m * NVEC + iv];

        f32x4 ov[RROWS];
#pragma unroll
        for (int j = 0; j < RROWS; ++j) ov[j] = (f32x4)(0.f);
#pragma unroll
        for (int m = 0; m < NM; ++m) {
#pragma unroll
            for (int j = 0; j < RROWS; ++j) {
                ov[j].x += p[j][m] * mv[m].x;
                ov[j].y += p[j][m] * mv[m].y;
                ov[j].z += p[j][m] * mv[m].z;
                ov[j].w += p[j][m] * mv[m].w;
            }
        }
#pragma unroll
        for (int j = 0; j < RROWS; ++j)
            __builtin_nontemporal_store(ov[j], &orow[j * NVEC + iv]);
    }
}

extern "C" void kernel_launch(void* const* d_in, const int* in_sizes, int n_in,
                              void* d_out, int out_size, void* d_ws, size_t ws_size,
                              hipStream_t stream) {
    const float* x   = (const float*)d_in[0];   // [32,256,88,88] f32
    const float* mem = (const float*)d_in[1];   // [10,88,88] f32
    float* out       = (float*)d_out;           // [32,256,88,88] f32
    float* probs     = (float*)d_ws;            // [8192][10] f32 = 328 KB

    const int rows   = 32 * 256;                // 8192
    const int blocks = rows / RROWS;            // 2048

    memaug_scores<<<blocks, THREADS, 0, stream>>>(x, mem, probs);
    memaug_apply <<<blocks, THREADS, 0, stream>>>(probs, mem, out);
}